// Round 5
// baseline (1483.806 us; speedup 1.0000x reference)
//
#include <hip/hip_runtime.h>
#include <hip/hip_bf16.h>
#include <math.h>

// B=32, T=128, D_IN=32, H1=1024, H=2048, PEN=1024, C=64, P=4
// Inputs/outputs are FLOAT32 (per the reference dtypes; labels int32).
// Internally: f32 -> bf16 conversion at GEMM staging, bf16 MFMA compute,
// bf16 activations, f32 final outputs. Loose threshold (1.02e-2) admits bf16.

typedef __bf16 bf16_t;
typedef __bf16 bf16x4 __attribute__((ext_vector_type(4)));
typedef __bf16 bf16x8 __attribute__((ext_vector_type(8)));
typedef float  f32x4  __attribute__((ext_vector_type(4)));

static __device__ __forceinline__ void zero4(f32x4& v) {
  v[0] = 0.0f; v[1] = 0.0f; v[2] = 0.0f; v[3] = 0.0f;
}

template <typename T>
static __device__ __forceinline__ bf16x8 load8_as_bf16(const T* p);
template <>
__device__ __forceinline__ bf16x8 load8_as_bf16<bf16_t>(const bf16_t* p) {
  return *(const bf16x8*)p;
}
template <>
__device__ __forceinline__ bf16x8 load8_as_bf16<float>(const float* p) {
  bf16x8 v;
#pragma unroll
  for (int u = 0; u < 8; ++u) v[u] = (bf16_t)p[u];
  return v;
}

// ---------------------------------------------------------------------------
// GEMM: C[M,N] = act(A[M,K] * Bm[N,K]^T + bias[N]), row-major, bf16 C.
// (unchanged from the 2618us baseline)
// ---------------------------------------------------------------------------
template <typename TA, typename TB>
__global__ __launch_bounds__(256) void gemm_bt(
    const TA* __restrict__ A, const TB* __restrict__ Bm,
    const float* __restrict__ bias, bf16_t* __restrict__ C,
    int M, int N, int K, int relu)
{
  __shared__ __align__(16) bf16_t As[128 * 32];
  __shared__ __align__(16) bf16_t Bs[128 * 32];

  const int tid  = threadIdx.x;
  const int lane = tid & 63;
  const int wave = tid >> 6;
  const int q    = lane >> 4;     // quad 0..3
  const int l15  = lane & 15;
  const int wr   = wave >> 1;     // wave m-half
  const int wc   = wave & 1;      // wave n-half
  const int m0   = blockIdx.y * 128;
  const int n0   = blockIdx.x * 128;

  f32x4 acc[4][4];
#pragma unroll
  for (int i = 0; i < 4; ++i)
#pragma unroll
    for (int j = 0; j < 4; ++j) zero4(acc[i][j]);

  const int se = wave * 512 + lane * 8;  // element in a 2048-elem chunk

  const int kt_count = K >> 5;
  for (int kt = 0; kt < kt_count; ++kt) {
    const int k0 = kt << 5;

    bf16x8 av[2], bv[2];
#pragma unroll
    for (int c = 0; c < 2; ++c) {
      const int e   = c * 2048 + se;
      const int row = e >> 5;      // 0..127
      const int col = e & 31;      // 0,8,16,24
      av[c] = load8_as_bf16<TA>(&A [(size_t)(m0 + row) * K + k0 + col]);
      bv[c] = load8_as_bf16<TB>(&Bm[(size_t)(n0 + row) * K + k0 + col]);
    }

    __syncthreads();   // previous iteration's LDS reads complete
#pragma unroll
    for (int c = 0; c < 2; ++c) {
      *(bf16x8*)&As[c * 2048 + se] = av[c];
      *(bf16x8*)&Bs[c * 2048 + se] = bv[c];
    }
    __syncthreads();   // staging visible to all waves

    bf16x8 af[4], bfv[4];
#pragma unroll
    for (int i = 0; i < 4; ++i)
      af[i] = *(const bf16x8*)&As[(wr * 64 + i * 16 + l15) * 32 + q * 8];
#pragma unroll
    for (int j = 0; j < 4; ++j)
      bfv[j] = *(const bf16x8*)&Bs[(wc * 64 + j * 16 + l15) * 32 + q * 8];

#pragma unroll
    for (int i = 0; i < 4; ++i)
#pragma unroll
      for (int j = 0; j < 4; ++j)
        acc[i][j] = __builtin_amdgcn_mfma_f32_16x16x32_bf16(af[i], bfv[j], acc[i][j], 0, 0, 0);
  }

  // Epilogue: C/D layout col = lane&15 (n), row = (lane>>4)*4 + reg (m)
#pragma unroll
  for (int j = 0; j < 4; ++j) {
    const int n = n0 + wc * 64 + j * 16 + l15;
    const float bvl = bias[n];
#pragma unroll
    for (int i = 0; i < 4; ++i) {
      const int mbase = m0 + wr * 64 + i * 16 + q * 4;
#pragma unroll
      for (int r = 0; r < 4; ++r) {
        float v = acc[i][j][r] + bvl;
        if (relu) v = v > 0.0f ? v : 0.0f;
        C[(size_t)(mbase + r) * N + n] = (bf16_t)v;
      }
    }
  }
}

// ---------------------------------------------------------------------------
// Persistent GRU scan, round 5.
// Round-4 post-mortem: VGPR_Count=84 but wf[3][8] needs 96 VGPRs alone ->
// the "register-resident" W NEVER materialized; the compiler spilled it
// to scratch / rematerialized per step (L2-absorbed, invisible in FETCH).
// That reload+cvt chain, serialized with MFMA, is the unexplained ~6us/step.
// Round-5: W in LDS as bf16 (provably resident), geometry that fits it:
//  - 256 WGs x 512 threads (8 waves = 2/SIMD) -> ALL 256 CUs (2x round 4).
//    WG owns 8 h-cols -> 24 gate rows. Ws = 24 x (2048+8) bf16 = 98.7 KB;
//    pad 8 puts the wave64 ds_read_b128 at the 8-cycle LDS floor.
//  - Wave owns K-slice 256: per step 16 ds_read_b128 (W) + 16-frag hprev
//    burst (64 VGPR, affordable now) + 32 MFMA + partial store.
//  - Partials hp_p[8][32][28] (28.7 KB); total LDS 127 KB -> 1 WG/CU.
//  - Sync identical to round 4 (per-wave producer flags; wave w's
//    producers = WGs [32w, 32w+32) = 2 cache lines of flags).
//  - Pointwise done by waves 0-3 (tid<256: 32 batches x 8 cols).
// ---------------------------------------------------------------------------
#define WROW 2056  // 2048 + 8 bf16 pad

__global__ __launch_bounds__(512, 2) void gru_persistent(
    const float* __restrict__ W_hh, const float* __restrict__ b_hh,
    const bf16_t* __restrict__ xp, bf16_t* __restrict__ hs,
    unsigned* __restrict__ arr)
{
  __shared__ __align__(16) bf16_t Ws[24 * WROW];    // 98,688 B
  __shared__ __align__(16) float hp_p[8][32][28];   // 28,672 B partials

  const int tid  = threadIdx.x;
  const int lane = tid & 63;
  const int wave = tid >> 6;      // K-slice owner, 0..7
  const int q    = lane >> 4;
  const int l15  = lane & 15;
  const int j0   = blockIdx.x * 8;
  const int k0w  = wave * 256;

  // ---- Stage this WG's W_hh slice into LDS once (f32 -> bf16) ----
  // Row m (0..23): gate = m>>3, source row = gate*2048 + j0 + (m&7).
  // 512 threads x 4 elems cover one 2048-wide row.
  for (int m = 0; m < 24; ++m) {
    const int gate = m >> 3;
    const float* src = W_hh + (size_t)(gate * 2048 + j0 + (m & 7)) * 2048;
    const int c = tid * 4;
    bf16x4 v;
#pragma unroll
    for (int u = 0; u < 4; ++u) v[u] = (bf16_t)src[c + u];
    *(bf16x4*)&Ws[m * WROW + c] = v;
  }

  // pointwise mapping: waves 0-3 (tid<256) -> (batch b, local col jj)
  const bool pw = tid < 256;
  const int b  = (tid >> 3) & 31; // 0..31 (valid when pw)
  const int jj = tid & 7;         // 0..7
  const int jg = j0 + jj;
  float bh_r = 0.f, bh_z = 0.f, bh_n = 0.f;
  if (pw) {
    bh_r = b_hh[jg];
    bh_z = b_hh[2048 + jg];
    bh_n = b_hh[4096 + jg];
  }

  // matmul A-tiles (W rows in LDS): tile0 row = l15 (gates r,z),
  // tile1 row = 16 + (l15&7) (gate n; upper lanes duplicate, discarded)
  const bf16_t* arow0 = &Ws[(size_t)l15 * WROW + k0w];
  const bf16_t* arow1 = &Ws[(size_t)(16 + (l15 & 7)) * WROW + k0w];

  float hcur = 0.0f;              // this thread's own h(b, jg)
  unsigned* hs32 = (unsigned*)hs;

  // xp for t=0
  float xr_c = 0.f, xz_c = 0.f, xn_c = 0.f;
  if (pw) {
    xr_c = (float)xp[(size_t)(b * 128 + 0) * 6144 + jg];
    xz_c = (float)xp[(size_t)(b * 128 + 0) * 6144 + 2048 + jg];
    xn_c = (float)xp[(size_t)(b * 128 + 0) * 6144 + 4096 + jg];
  }

  __syncthreads();   // Ws staged

  for (int t = 0; t < 128; ++t) {
    if (t > 0) {
      // ---- hprev fragment burst: 16 independent 16B loads ----
      bf16x8 bfr[2][8];
#pragma unroll
      for (int ct = 0; ct < 2; ++ct) {
        const bf16_t* bp_ = hs + ((size_t)(ct * 16 + l15) * 128 + (t - 1)) * 2048
                               + k0w + q * 8;
#pragma unroll
        for (int win = 0; win < 8; ++win)
          bfr[ct][win] = *(const bf16x8*)(bp_ + win * 32);
      }

      f32x4 acc[2][2];
#pragma unroll
      for (int rt = 0; rt < 2; ++rt)
#pragma unroll
        for (int ct = 0; ct < 2; ++ct) zero4(acc[rt][ct]);

#pragma unroll
      for (int win = 0; win < 8; ++win) {
        const bf16x8 a0 = *(const bf16x8*)(arow0 + win * 32 + q * 8);
        const bf16x8 a1 = *(const bf16x8*)(arow1 + win * 32 + q * 8);
        acc[0][0] = __builtin_amdgcn_mfma_f32_16x16x32_bf16(a0, bfr[0][win], acc[0][0], 0, 0, 0);
        acc[0][1] = __builtin_amdgcn_mfma_f32_16x16x32_bf16(a0, bfr[1][win], acc[0][1], 0, 0, 0);
        acc[1][0] = __builtin_amdgcn_mfma_f32_16x16x32_bf16(a1, bfr[0][win], acc[1][0], 0, 0, 0);
        acc[1][1] = __builtin_amdgcn_mfma_f32_16x16x32_bf16(a1, bfr[1][win], acc[1][1], 0, 0, 0);
      }

      // partials: D col = l15 (batch within ct-tile), row = q*4+reg
#pragma unroll
      for (int ct = 0; ct < 2; ++ct) {
        *(f32x4*)&hp_p[wave][ct * 16 + l15][q * 4] = acc[0][ct];
        if (q < 2)  // tile1 rows 16..23 only
          *(f32x4*)&hp_p[wave][ct * 16 + l15][16 + q * 4] = acc[1][ct];
      }
    }
    __syncthreads();   // partials visible (and prev-step LDS reuse safe)

    if (pw) {
      float pr = 0.0f, pz = 0.0f, pn = 0.0f;
      if (t > 0) {
#pragma unroll
        for (int w = 0; w < 8; ++w) {
          pr += hp_p[w][b][jj];
          pz += hp_p[w][b][8 + jj];
          pn += hp_p[w][b][16 + jj];
        }
      }
      const float r_ = 1.0f / (1.0f + __expf(-(xr_c + pr + bh_r)));
      const float z_ = 1.0f / (1.0f + __expf(-(xz_c + pz + bh_z)));
      // fast tanh: tanh(a) = (1 - e^{-2a}) / (1 + e^{-2a})
      const float aa = xn_c + r_ * (pn + bh_n);
      const float et = __expf(-2.0f * aa);
      const float n_ = (1.0f - et) / (1.0f + et);
      hcur = (1.0f - z_) * n_ + z_ * hcur;

      // pack lane-pair (jj even/odd, same b) into u32, agent-scope store
      union { bf16_t h; unsigned short u; } cv; cv.h = (bf16_t)hcur;
      const unsigned hv = cv.u;
      const unsigned ov = (unsigned)__shfl_xor((int)hv, 1, 64);
      if ((tid & 1) == 0) {
        const unsigned pk = hv | (ov << 16);
        const size_t widx = ((size_t)b * 128 + t) * 1024 + (jg >> 1);
        __hip_atomic_store(hs32 + widx, pk, __ATOMIC_RELAXED,
                           __HIP_MEMORY_SCOPE_AGENT);
      }
    }

    if (t < 127) {
      // ---- producer-sliced grid sync ----
      asm volatile("s_waitcnt vmcnt(0)" ::: "memory");  // hs stores at LLC
      __syncthreads();   // (A) whole WG drained; step-t LDS reads done
      if (tid == 0)
        __hip_atomic_store(arr + (size_t)t * 256 + blockIdx.x, 1u,
                           __ATOMIC_RELAXED, __HIP_MEMORY_SCOPE_AGENT);
      // prefetch xp for t+1: latency hides under the poll
      const int tn = t + 1;
      float xr_n = 0.f, xz_n = 0.f, xn_n = 0.f;
      if (pw) {
        xr_n = (float)xp[(size_t)(b * 128 + tn) * 6144 + jg];
        xz_n = (float)xp[(size_t)(b * 128 + tn) * 6144 + 2048 + jg];
        xn_n = (float)xp[(size_t)(b * 128 + tn) * 6144 + 4096 + jg];
      }
      asm volatile("" ::: "memory");   // pin prefetch before the spin

      // wave w waits only for ITS producers: WGs 32w..32w+31 (2 lines)
      const unsigned long long* f64p =
          (const unsigned long long*)(arr + (size_t)t * 256) + wave * 16;
      const unsigned long long tgt = 0x0000000100000001ull;
      int guard = 0;
      for (;;) {
        unsigned long long v = tgt;
        if (lane < 16)
          v = __hip_atomic_load(f64p + lane, __ATOMIC_RELAXED,
                                __HIP_MEMORY_SCOPE_AGENT);
        if (__all(v == tgt)) break;
        __builtin_amdgcn_s_sleep(1);
        if (++guard > (1 << 20)) break;   // safety: never hang
      }
      // no trailing syncthreads: each wave proceeds as soon as its
      // producer slice of hs[t] is globally visible.

      xr_c = xr_n; xz_c = xz_n; xn_c = xn_n;
    }
  }
}

// ---------------------------------------------------------------------------
// Heads: per (b,t): 3 scalar heads + 4 sigmoid heads, 1024-dot each with a
// label-gathered f32 weight row. out_s is bf16, OUTPUT IS FLOAT32.
// ---------------------------------------------------------------------------
__global__ __launch_bounds__(256) void heads_kernel(
    const bf16_t* __restrict__ out_s, const int* __restrict__ labels,
    const float* __restrict__ W4, const float* __restrict__ b4,
    const float* __restrict__ W5, const float* __restrict__ b5,
    const float* __restrict__ W6, const float* __restrict__ b6,
    const float* __restrict__ Wp, const float* __restrict__ bp,
    float* __restrict__ out)
{
  const int bt  = blockIdx.x;
  const int b   = bt >> 7;         // T = 128
  const int lab = labels[b];
  const bf16_t* os  = out_s + (size_t)bt * 1024;
  const float* w4  = W4 + (size_t)lab * 1024;
  const float* w5  = W5 + (size_t)lab * 1024;
  const float* w6  = W6 + (size_t)lab * 1024;
  const float* wp0 = Wp + (size_t)lab * 1024;   // + p*65536 for plane p

  float s[7] = {0, 0, 0, 0, 0, 0, 0};
  for (int d = threadIdx.x; d < 1024; d += 256) {
    const float v = (float)os[d];
    s[0] += v * w4[d];
    s[1] += v * w5[d];
    s[2] += v * w6[d];
    s[3] += v * wp0[d];
    s[4] += v * wp0[65536 + d];
    s[5] += v * wp0[131072 + d];
    s[6] += v * wp0[196608 + d];
  }
#pragma unroll
  for (int i = 0; i < 7; ++i)
    for (int off = 32; off > 0; off >>= 1)
      s[i] += __shfl_down(s[i], off, 64);

  __shared__ float red[4][7];
  const int lane = threadIdx.x & 63, wave = threadIdx.x >> 6;
  if (lane == 0)
    for (int i = 0; i < 7; ++i) red[wave][i] = s[i];
  __syncthreads();
  if (threadIdx.x == 0) {
    float tsum[7];
    for (int i = 0; i < 7; ++i)
      tsum[i] = red[0][i] + red[1][i] + red[2][i] + red[3][i];
    out[bt]        = tsum[0] + b4[lab];
    out[4096 + bt] = tsum[1] + b5[lab];
    out[8192 + bt] = tsum[2] + b6[lab];
#pragma unroll
    for (int p = 0; p < 4; ++p) {
      const float v = tsum[3 + p] + bp[p * 64 + lab];
      out[12288 + p * 4096 + bt] = 1.0f / (1.0f + __expf(-v));
    }
  }
}

// ---------------------------------------------------------------------------
extern "C" void kernel_launch(void* const* d_in, const int* in_sizes, int n_in,
                              void* d_out, int out_size, void* d_ws, size_t ws_size,
                              hipStream_t stream)
{
  const float* x     = (const float*)d_in[0];
  const int*   label = (const int*)d_in[1];
  const float* W1    = (const float*)d_in[2];
  const float* b1    = (const float*)d_in[3];
  const float* W2    = (const float*)d_in[4];
  const float* b2    = (const float*)d_in[5];
  const float* W_ih  = (const float*)d_in[6];
  const float* b_ih  = (const float*)d_in[7];
  const float* W_hh  = (const float*)d_in[8];
  const float* b_hh  = (const float*)d_in[9];
  const float* W3    = (const float*)d_in[10];
  const float* b3    = (const float*)d_in[11];
  const float* W4    = (const float*)d_in[12];
  const float* b4    = (const float*)d_in[13];
  const float* W5    = (const float*)d_in[14];
  const float* b5    = (const float*)d_in[15];
  const float* W6    = (const float*)d_in[16];
  const float* b6    = (const float*)d_in[17];
  const float* Wp    = (const float*)d_in[18];
  const float* bp    = (const float*)d_in[19];

  // Workspace map (96 MB), bf16 internals:
  //   arr   [0, 128KB) 128x256 u32 per-step arrival flags (memset 0)
  //   out1  [24,32MB)  4096x1024  — dead after layer2
  //   out2  [32,48MB)  4096x2048  — dead after xp GEMM
  //   xp    [48,96MB)  4096x6144  — live through GRU
  //   hs    [24,40MB)  (B,T,2048) — overlays out1+out2-head (dead)
  //   out_s [40,48MB)  4096x1024  — overlays out2 tail (dead)
  char* ws = (char*)d_ws;
  unsigned* arr = (unsigned*)ws;
  bf16_t* out1  = (bf16_t*)(ws + (24u << 20));
  bf16_t* out2  = (bf16_t*)(ws + (32u << 20));
  bf16_t* xp    = (bf16_t*)(ws + (48u << 20));
  bf16_t* hs    = (bf16_t*)(ws + (24u << 20));
  bf16_t* out_s = (bf16_t*)(ws + (40u << 20));
  float*  outp  = (float*)d_out;

  hipMemsetAsync(d_out, 0, (size_t)out_size * sizeof(float), stream);
  hipMemsetAsync(ws, 0, 131072, stream);   // arrival flags

  dim3 blk(256);
  // layer1: (4096x32)*(1024x32)^T, relu
  gemm_bt<float, float><<<dim3(8, 32), blk, 0, stream>>>(x, W1, b1, out1, 4096, 1024, 32, 1);
  // layer2: (4096x1024)*(2048x1024)^T, relu
  gemm_bt<bf16_t, float><<<dim3(16, 32), blk, 0, stream>>>(out1, W2, b2, out2, 4096, 2048, 1024, 1);
  // xp: (4096x2048)*(6144x2048)^T + b_ih
  gemm_bt<bf16_t, float><<<dim3(48, 32), blk, 0, stream>>>(out2, W_ih, b_ih, xp, 4096, 6144, 2048, 0);
  // GRU scan: persistent kernel, LDS-resident bf16 W, producer-sliced sync.
  // 256 WGs x 512 threads -> 1 WG/CU on all 256 CUs (127 KB LDS pins it).
  {
    void* gru_args[] = { (void*)&W_hh, (void*)&b_hh, (void*)&xp, (void*)&hs,
                         (void*)&arr };
    hipLaunchCooperativeKernel((void*)gru_persistent, dim3(256), dim3(512),
                               gru_args, 0, stream);
  }
  // layer3: (4096x2048)*(1024x2048)^T, relu
  gemm_bt<bf16_t, float><<<dim3(8, 32), blk, 0, stream>>>(hs, W3, b3, out_s, 4096, 1024, 2048, 1);
  // heads (f32 weights, f32 out)
  heads_kernel<<<dim3(4096), blk, 0, stream>>>(out_s, label, W4, b4, W5, b5, W6, b6, Wp, bp, outp);
}

// Round 6
// 1337.689 us; speedup vs baseline: 1.1092x; 1.1092x over previous
//
#include <hip/hip_runtime.h>
#include <hip/hip_bf16.h>
#include <math.h>

// B=32, T=128, D_IN=32, H1=1024, H=2048, PEN=1024, C=64, P=4
// Inputs/outputs are FLOAT32 (per the reference dtypes; labels int32).
// Internally: f32 -> bf16 conversion at GEMM staging, bf16 MFMA compute,
// bf16 activations, f32 final outputs. Loose threshold (1.02e-2) admits bf16.

typedef __bf16 bf16_t;
typedef __bf16 bf16x4 __attribute__((ext_vector_type(4)));
typedef __bf16 bf16x8 __attribute__((ext_vector_type(8)));
typedef float  f32x4  __attribute__((ext_vector_type(4)));
typedef int    i32x4  __attribute__((ext_vector_type(4)));

static __device__ __forceinline__ void zero4(f32x4& v) {
  v[0] = 0.0f; v[1] = 0.0f; v[2] = 0.0f; v[3] = 0.0f;
}

template <typename T>
static __device__ __forceinline__ bf16x8 load8_as_bf16(const T* p);
template <>
__device__ __forceinline__ bf16x8 load8_as_bf16<bf16_t>(const bf16_t* p) {
  return *(const bf16x8*)p;
}
template <>
__device__ __forceinline__ bf16x8 load8_as_bf16<float>(const float* p) {
  bf16x8 v;
#pragma unroll
  for (int u = 0; u < 8; ++u) v[u] = (bf16_t)p[u];
  return v;
}

// ---------------------------------------------------------------------------
// GEMM: C[M,N] = act(A[M,K] * Bm[N,K]^T + bias[N]), row-major, bf16 C.
// (unchanged from the 2618us baseline)
// ---------------------------------------------------------------------------
template <typename TA, typename TB>
__global__ __launch_bounds__(256) void gemm_bt(
    const TA* __restrict__ A, const TB* __restrict__ Bm,
    const float* __restrict__ bias, bf16_t* __restrict__ C,
    int M, int N, int K, int relu)
{
  __shared__ __align__(16) bf16_t As[128 * 32];
  __shared__ __align__(16) bf16_t Bs[128 * 32];

  const int tid  = threadIdx.x;
  const int lane = tid & 63;
  const int wave = tid >> 6;
  const int q    = lane >> 4;     // quad 0..3
  const int l15  = lane & 15;
  const int wr   = wave >> 1;     // wave m-half
  const int wc   = wave & 1;      // wave n-half
  const int m0   = blockIdx.y * 128;
  const int n0   = blockIdx.x * 128;

  f32x4 acc[4][4];
#pragma unroll
  for (int i = 0; i < 4; ++i)
#pragma unroll
    for (int j = 0; j < 4; ++j) zero4(acc[i][j]);

  const int se = wave * 512 + lane * 8;  // element in a 2048-elem chunk

  const int kt_count = K >> 5;
  for (int kt = 0; kt < kt_count; ++kt) {
    const int k0 = kt << 5;

    bf16x8 av[2], bv[2];
#pragma unroll
    for (int c = 0; c < 2; ++c) {
      const int e   = c * 2048 + se;
      const int row = e >> 5;      // 0..127
      const int col = e & 31;      // 0,8,16,24
      av[c] = load8_as_bf16<TA>(&A [(size_t)(m0 + row) * K + k0 + col]);
      bv[c] = load8_as_bf16<TB>(&Bm[(size_t)(n0 + row) * K + k0 + col]);
    }

    __syncthreads();   // previous iteration's LDS reads complete
#pragma unroll
    for (int c = 0; c < 2; ++c) {
      *(bf16x8*)&As[c * 2048 + se] = av[c];
      *(bf16x8*)&Bs[c * 2048 + se] = bv[c];
    }
    __syncthreads();   // staging visible to all waves

    bf16x8 af[4], bfv[4];
#pragma unroll
    for (int i = 0; i < 4; ++i)
      af[i] = *(const bf16x8*)&As[(wr * 64 + i * 16 + l15) * 32 + q * 8];
#pragma unroll
    for (int j = 0; j < 4; ++j)
      bfv[j] = *(const bf16x8*)&Bs[(wc * 64 + j * 16 + l15) * 32 + q * 8];

#pragma unroll
    for (int i = 0; i < 4; ++i)
#pragma unroll
      for (int j = 0; j < 4; ++j)
        acc[i][j] = __builtin_amdgcn_mfma_f32_16x16x32_bf16(af[i], bfv[j], acc[i][j], 0, 0, 0);
  }

  // Epilogue: C/D layout col = lane&15 (n), row = (lane>>4)*4 + reg (m)
#pragma unroll
  for (int j = 0; j < 4; ++j) {
    const int n = n0 + wc * 64 + j * 16 + l15;
    const float bvl = bias[n];
#pragma unroll
    for (int i = 0; i < 4; ++i) {
      const int mbase = m0 + wr * 64 + i * 16 + q * 4;
#pragma unroll
      for (int r = 0; r < 4; ++r) {
        float v = acc[i][j][r] + bvl;
        if (relu) v = v > 0.0f ? v : 0.0f;
        C[(size_t)(mbase + r) * N + n] = (bf16_t)v;
      }
    }
  }
}

// ---------------------------------------------------------------------------
// Persistent GRU scan, round 6.
// Round-5 post-mortem: 3 sync topologies all ~8us/step. Remaining modeled
// slop = TRANSACTION COUNTS, not hop latency:
//  (1) h stores were 128 scattered 4B agent-atomics per WG (32K non-
//      coalescing LLC transactions/step device-wide) and the vmcnt(0)
//      drain waits for the slowest of them;
//  (2) 2048 waves polled ~8 LLC flag lines -> producers' flag stores
//      queue behind the read storm.
// Round-6 changes:
//  - Packed h stores: pointwise threads write bf16 to an LDS stage;
//    wave 0's 32 lanes each emit ONE global_store_dwordx4 sc0 sc1
//    (batch's 8 cols = 16B). 32 coalesced stores/WG vs 128 atomics.
//    Only wave 0 drains (one burst) and publishes flags.
//  - Flags replicated NCOPY=8x; consumer wave polls copy (bid&7):
//    per-line poller count drops ~16x.
//  - Waves 1-7 free-run from barrier (A) straight into the next step's
//    poll, overlapping wave 0's drain+flag. Single hp_p buffer is safe:
//    all pointwise reads of hp_p precede (A); all next-step deposits
//    follow it.
//  - xp prefetch issued before (A) so it rides under drain+poll.
// ---------------------------------------------------------------------------
#define WROW 2056   // 2048 + 8 bf16 pad
#define NCOPY 8

__global__ __launch_bounds__(512, 2) void gru_persistent(
    const float* __restrict__ W_hh, const float* __restrict__ b_hh,
    const bf16_t* __restrict__ xp, bf16_t* __restrict__ hs,
    unsigned* __restrict__ arr)
{
  __shared__ __align__(16) bf16_t Ws[24 * WROW];            // 98,688 B
  __shared__ __align__(16) float hp_p[8][32][28];           // 28,672 B
  __shared__ __align__(16) unsigned short stage[32][8];     //    512 B

  const int tid  = threadIdx.x;
  const int lane = tid & 63;
  const int wave = tid >> 6;      // K-slice owner, 0..7
  const int q    = lane >> 4;
  const int l15  = lane & 15;
  const int bid  = blockIdx.x;
  const int j0   = bid * 8;
  const int k0w  = wave * 256;

  // ---- Stage this WG's W_hh slice into LDS once (f32 -> bf16) ----
  for (int m = 0; m < 24; ++m) {
    const int gate = m >> 3;
    const float* src = W_hh + (size_t)(gate * 2048 + j0 + (m & 7)) * 2048;
    const int c = tid * 4;
    bf16x4 v;
#pragma unroll
    for (int u = 0; u < 4; ++u) v[u] = (bf16_t)src[c + u];
    *(bf16x4*)&Ws[m * WROW + c] = v;
  }

  // pointwise mapping: waves 0-3 (tid<256) -> (batch b, local col jj)
  const bool pw = tid < 256;
  const int b  = (tid >> 3) & 31;
  const int jj = tid & 7;
  const int jg = j0 + jj;
  float bh_r = 0.f, bh_z = 0.f, bh_n = 0.f;
  if (pw) {
    bh_r = b_hh[jg];
    bh_z = b_hh[2048 + jg];
    bh_n = b_hh[4096 + jg];
  }

  // matmul A-tiles (W rows in LDS): tile0 row = l15 (gates r,z),
  // tile1 row = 16 + (l15&7) (gate n; upper-half lanes duplicate)
  const bf16_t* arow0 = &Ws[(size_t)l15 * WROW + k0w];
  const bf16_t* arow1 = &Ws[(size_t)(16 + (l15 & 7)) * WROW + k0w];

  float hcur = 0.0f;              // this thread's own h(b, jg)

  // xp for t=0
  float xr_c = 0.f, xz_c = 0.f, xn_c = 0.f;
  if (pw) {
    xr_c = (float)xp[(size_t)(b * 128 + 0) * 6144 + jg];
    xz_c = (float)xp[(size_t)(b * 128 + 0) * 6144 + 2048 + jg];
    xn_c = (float)xp[(size_t)(b * 128 + 0) * 6144 + 4096 + jg];
  }

  __syncthreads();   // Ws staged

  for (int t = 0; t < 128; ++t) {
    if (t > 0) {
      // ---- poll own producer slice of h[t-1] flags (copy bid&7) ----
      const int c = bid & 7;
      const unsigned long long* f64p =
          (const unsigned long long*)(arr + ((size_t)(t - 1) * NCOPY + c) * 256)
          + wave * 16;
      const unsigned long long tgt = 0x0000000100000001ull;
      int guard = 0;
      for (;;) {
        unsigned long long v = tgt;
        if (lane < 16)
          v = __hip_atomic_load(f64p + lane, __ATOMIC_RELAXED,
                                __HIP_MEMORY_SCOPE_AGENT);
        if (__all(v == tgt)) break;
        __builtin_amdgcn_s_sleep(1);
        if (++guard > (1 << 20)) break;   // safety: never hang
      }

      // ---- hprev fragment burst: 16 independent 16B loads ----
      bf16x8 bfr[2][8];
#pragma unroll
      for (int ct = 0; ct < 2; ++ct) {
        const bf16_t* bp_ = hs + ((size_t)(ct * 16 + l15) * 128 + (t - 1)) * 2048
                               + k0w + q * 8;
#pragma unroll
        for (int win = 0; win < 8; ++win)
          bfr[ct][win] = *(const bf16x8*)(bp_ + win * 32);
      }

      f32x4 acc[2][2];
#pragma unroll
      for (int rt = 0; rt < 2; ++rt)
#pragma unroll
        for (int ct = 0; ct < 2; ++ct) zero4(acc[rt][ct]);

#pragma unroll
      for (int win = 0; win < 8; ++win) {
        const bf16x8 a0 = *(const bf16x8*)(arow0 + win * 32 + q * 8);
        const bf16x8 a1 = *(const bf16x8*)(arow1 + win * 32 + q * 8);
        acc[0][0] = __builtin_amdgcn_mfma_f32_16x16x32_bf16(a0, bfr[0][win], acc[0][0], 0, 0, 0);
        acc[0][1] = __builtin_amdgcn_mfma_f32_16x16x32_bf16(a0, bfr[1][win], acc[0][1], 0, 0, 0);
        acc[1][0] = __builtin_amdgcn_mfma_f32_16x16x32_bf16(a1, bfr[0][win], acc[1][0], 0, 0, 0);
        acc[1][1] = __builtin_amdgcn_mfma_f32_16x16x32_bf16(a1, bfr[1][win], acc[1][1], 0, 0, 0);
      }

      // partials: D col = l15 (batch within ct-tile), row = q*4+reg
#pragma unroll
      for (int ct = 0; ct < 2; ++ct) {
        *(f32x4*)&hp_p[wave][ct * 16 + l15][q * 4] = acc[0][ct];
        if (q < 2)  // tile1 rows 16..23 only
          *(f32x4*)&hp_p[wave][ct * 16 + l15][16 + q * 4] = acc[1][ct];
      }
    }
    __syncthreads();   // (B) partials ready

    float xr_n = 0.f, xz_n = 0.f, xn_n = 0.f;
    if (pw) {
      float pr = 0.0f, pz = 0.0f, pn = 0.0f;
      if (t > 0) {
#pragma unroll
        for (int w = 0; w < 8; ++w) {
          pr += hp_p[w][b][jj];
          pz += hp_p[w][b][8 + jj];
          pn += hp_p[w][b][16 + jj];
        }
      }
      const float r_ = 1.0f / (1.0f + __expf(-(xr_c + pr + bh_r)));
      const float z_ = 1.0f / (1.0f + __expf(-(xz_c + pz + bh_z)));
      // fast tanh: tanh(a) = (1 - e^{-2a}) / (1 + e^{-2a})
      const float aa = xn_c + r_ * (pn + bh_n);
      const float et = __expf(-2.0f * aa);
      const float n_ = (1.0f - et) / (1.0f + et);
      hcur = (1.0f - z_) * n_ + z_ * hcur;

      // xp prefetch for t+1: latency hides under drain + poll
      if (t < 127) {
        const int tn = t + 1;
        xr_n = (float)xp[(size_t)(b * 128 + tn) * 6144 + jg];
        xz_n = (float)xp[(size_t)(b * 128 + tn) * 6144 + 2048 + jg];
        xn_n = (float)xp[(size_t)(b * 128 + tn) * 6144 + 4096 + jg];
      }

      // stage h for the packed store
      union { bf16_t h; unsigned short u; } cv; cv.h = (bf16_t)hcur;
      stage[b][jj] = cv.u;
    }
    __syncthreads();   // (A) stage ready; all hp_p reads of step t done

    // ---- packed h store: wave 0 only, 32 x 16B coalesced sc0sc1 ----
    if (wave == 0 && lane < 32) {
      const i32x4 val = *(const i32x4*)&stage[lane][0];
      bf16_t* dst = hs + ((size_t)lane * 128 + t) * 2048 + j0;
      asm volatile("global_store_dwordx4 %0, %1, off sc0 sc1"
                   :: "v"(dst), "v"(val) : "memory");
    }
    if (t < 127) {
      if (wave == 0) {
        asm volatile("s_waitcnt vmcnt(0)" ::: "memory");  // stores at LLC
        if (lane < NCOPY)
          __hip_atomic_store(arr + ((size_t)t * NCOPY + lane) * 256 + bid, 1u,
                             __ATOMIC_RELAXED, __HIP_MEMORY_SCOPE_AGENT);
      }
      // waves 1-7 free-run into the next step's poll here
      xr_c = xr_n; xz_c = xz_n; xn_c = xn_n;
    }
  }
}

// ---------------------------------------------------------------------------
// Heads: per (b,t): 3 scalar heads + 4 sigmoid heads, 1024-dot each with a
// label-gathered f32 weight row. out_s is bf16, OUTPUT IS FLOAT32.
// ---------------------------------------------------------------------------
__global__ __launch_bounds__(256) void heads_kernel(
    const bf16_t* __restrict__ out_s, const int* __restrict__ labels,
    const float* __restrict__ W4, const float* __restrict__ b4,
    const float* __restrict__ W5, const float* __restrict__ b5,
    const float* __restrict__ W6, const float* __restrict__ b6,
    const float* __restrict__ Wp, const float* __restrict__ bp,
    float* __restrict__ out)
{
  const int bt  = blockIdx.x;
  const int b   = bt >> 7;         // T = 128
  const int lab = labels[b];
  const bf16_t* os  = out_s + (size_t)bt * 1024;
  const float* w4  = W4 + (size_t)lab * 1024;
  const float* w5  = W5 + (size_t)lab * 1024;
  const float* w6  = W6 + (size_t)lab * 1024;
  const float* wp0 = Wp + (size_t)lab * 1024;   // + p*65536 for plane p

  float s[7] = {0, 0, 0, 0, 0, 0, 0};
  for (int d = threadIdx.x; d < 1024; d += 256) {
    const float v = (float)os[d];
    s[0] += v * w4[d];
    s[1] += v * w5[d];
    s[2] += v * w6[d];
    s[3] += v * wp0[d];
    s[4] += v * wp0[65536 + d];
    s[5] += v * wp0[131072 + d];
    s[6] += v * wp0[196608 + d];
  }
#pragma unroll
  for (int i = 0; i < 7; ++i)
    for (int off = 32; off > 0; off >>= 1)
      s[i] += __shfl_down(s[i], off, 64);

  __shared__ float red[4][7];
  const int lane = threadIdx.x & 63, wave = threadIdx.x >> 6;
  if (lane == 0)
    for (int i = 0; i < 7; ++i) red[wave][i] = s[i];
  __syncthreads();
  if (threadIdx.x == 0) {
    float tsum[7];
    for (int i = 0; i < 7; ++i)
      tsum[i] = red[0][i] + red[1][i] + red[2][i] + red[3][i];
    out[bt]        = tsum[0] + b4[lab];
    out[4096 + bt] = tsum[1] + b5[lab];
    out[8192 + bt] = tsum[2] + b6[lab];
#pragma unroll
    for (int p = 0; p < 4; ++p) {
      const float v = tsum[3 + p] + bp[p * 64 + lab];
      out[12288 + p * 4096 + bt] = 1.0f / (1.0f + __expf(-v));
    }
  }
}

// ---------------------------------------------------------------------------
extern "C" void kernel_launch(void* const* d_in, const int* in_sizes, int n_in,
                              void* d_out, int out_size, void* d_ws, size_t ws_size,
                              hipStream_t stream)
{
  const float* x     = (const float*)d_in[0];
  const int*   label = (const int*)d_in[1];
  const float* W1    = (const float*)d_in[2];
  const float* b1    = (const float*)d_in[3];
  const float* W2    = (const float*)d_in[4];
  const float* b2    = (const float*)d_in[5];
  const float* W_ih  = (const float*)d_in[6];
  const float* b_ih  = (const float*)d_in[7];
  const float* W_hh  = (const float*)d_in[8];
  const float* b_hh  = (const float*)d_in[9];
  const float* W3    = (const float*)d_in[10];
  const float* b3    = (const float*)d_in[11];
  const float* W4    = (const float*)d_in[12];
  const float* b4    = (const float*)d_in[13];
  const float* W5    = (const float*)d_in[14];
  const float* b5    = (const float*)d_in[15];
  const float* W6    = (const float*)d_in[16];
  const float* b6    = (const float*)d_in[17];
  const float* Wp    = (const float*)d_in[18];
  const float* bp    = (const float*)d_in[19];

  // Workspace map (96 MB), bf16 internals:
  //   arr   [0, 1MB)   128 x NCOPY x 256 u32 arrival flags (memset 0)
  //   out1  [24,32MB)  4096x1024  — dead after layer2
  //   out2  [32,48MB)  4096x2048  — dead after xp GEMM
  //   xp    [48,96MB)  4096x6144  — live through GRU
  //   hs    [24,40MB)  (B,T,2048) — overlays out1+out2-head (dead)
  //   out_s [40,48MB)  4096x1024  — overlays out2 tail (dead)
  char* ws = (char*)d_ws;
  unsigned* arr = (unsigned*)ws;
  bf16_t* out1  = (bf16_t*)(ws + (24u << 20));
  bf16_t* out2  = (bf16_t*)(ws + (32u << 20));
  bf16_t* xp    = (bf16_t*)(ws + (48u << 20));
  bf16_t* hs    = (bf16_t*)(ws + (24u << 20));
  bf16_t* out_s = (bf16_t*)(ws + (40u << 20));
  float*  outp  = (float*)d_out;

  hipMemsetAsync(d_out, 0, (size_t)out_size * sizeof(float), stream);
  hipMemsetAsync(ws, 0, 1u << 20, stream);   // arrival flags

  dim3 blk(256);
  // layer1: (4096x32)*(1024x32)^T, relu
  gemm_bt<float, float><<<dim3(8, 32), blk, 0, stream>>>(x, W1, b1, out1, 4096, 1024, 32, 1);
  // layer2: (4096x1024)*(2048x1024)^T, relu
  gemm_bt<bf16_t, float><<<dim3(16, 32), blk, 0, stream>>>(out1, W2, b2, out2, 4096, 2048, 1024, 1);
  // xp: (4096x2048)*(6144x2048)^T + b_ih
  gemm_bt<bf16_t, float><<<dim3(48, 32), blk, 0, stream>>>(out2, W_ih, b_ih, xp, 4096, 6144, 2048, 0);
  // GRU scan: persistent kernel, LDS-resident bf16 W, packed 16B h-stores,
  // replicated flags, free-running non-store waves.
  {
    void* gru_args[] = { (void*)&W_hh, (void*)&b_hh, (void*)&xp, (void*)&hs,
                         (void*)&arr };
    hipLaunchCooperativeKernel((void*)gru_persistent, dim3(256), dim3(512),
                               gru_args, 0, stream);
  }
  // layer3: (4096x2048)*(1024x2048)^T, relu
  gemm_bt<bf16_t, float><<<dim3(8, 32), blk, 0, stream>>>(hs, W3, b3, out_s, 4096, 1024, 2048, 1);
  // heads (f32 weights, f32 out)
  heads_kernel<<<dim3(4096), blk, 0, stream>>>(out_s, label, W4, b4, W5, b5, W6, b6, Wp, bp, outp);
}

// Round 7
// 1273.956 us; speedup vs baseline: 1.1647x; 1.0500x over previous
//
#include <hip/hip_runtime.h>
#include <hip/hip_bf16.h>
#include <math.h>

// B=32, T=128, D_IN=32, H1=1024, H=2048, PEN=1024, C=64, P=4
// Inputs/outputs are FLOAT32 (per the reference dtypes; labels int32).
// Internally: f32 -> bf16 conversion at GEMM staging, bf16 MFMA compute,
// bf16 activations, f32 final outputs. Loose threshold (1.02e-2) admits bf16.

typedef __bf16 bf16_t;
typedef __bf16 bf16x4 __attribute__((ext_vector_type(4)));
typedef __bf16 bf16x8 __attribute__((ext_vector_type(8)));
typedef float  f32x4  __attribute__((ext_vector_type(4)));
typedef int    i32x4  __attribute__((ext_vector_type(4)));
typedef unsigned int u32;

static __device__ __forceinline__ void zero4(f32x4& v) {
  v[0] = 0.0f; v[1] = 0.0f; v[2] = 0.0f; v[3] = 0.0f;
}

template <typename T>
static __device__ __forceinline__ bf16x8 load8_as_bf16(const T* p);
template <>
__device__ __forceinline__ bf16x8 load8_as_bf16<bf16_t>(const bf16_t* p) {
  return *(const bf16x8*)p;
}
template <>
__device__ __forceinline__ bf16x8 load8_as_bf16<float>(const float* p) {
  bf16x8 v;
#pragma unroll
  for (int u = 0; u < 8; ++u) v[u] = (bf16_t)p[u];
  return v;
}

// async global->LDS 16B copy: LDS dest is wave-uniform base + lane*16 (HW),
// global src is per-lane.
static __device__ __forceinline__ void gload16(const bf16_t* g, bf16_t* l) {
  __builtin_amdgcn_global_load_lds(
      (const __attribute__((address_space(1))) u32*)g,
      (__attribute__((address_space(3))) u32*)l, 16, 0, 0);
}

// ---------------------------------------------------------------------------
// f32 -> bf16 bulk convert (8 elems/thread). n8 = n/8.
// ---------------------------------------------------------------------------
__global__ __launch_bounds__(256) void cvt_f32_bf16(
    const float* __restrict__ s, bf16_t* __restrict__ d, int n8)
{
  const int i = blockIdx.x * 256 + threadIdx.x;
  if (i < n8) {
    const float* p = s + (size_t)i * 8;
    bf16x8 v;
#pragma unroll
    for (int u = 0; u < 8; ++u) v[u] = (bf16_t)p[u];
    *(bf16x8*)(d + (size_t)i * 8) = v;
  }
}

// ---------------------------------------------------------------------------
// GEMM (f32 path, layer1 only): C = act(A*B^T + bias), 128x128 tile, BK=32.
// ---------------------------------------------------------------------------
template <typename TA, typename TB>
__global__ __launch_bounds__(256) void gemm_bt(
    const TA* __restrict__ A, const TB* __restrict__ Bm,
    const float* __restrict__ bias, bf16_t* __restrict__ C,
    int M, int N, int K, int relu)
{
  __shared__ __align__(16) bf16_t As[128 * 32];
  __shared__ __align__(16) bf16_t Bs[128 * 32];

  const int tid  = threadIdx.x;
  const int lane = tid & 63;
  const int wave = tid >> 6;
  const int q    = lane >> 4;
  const int l15  = lane & 15;
  const int wr   = wave >> 1;
  const int wc   = wave & 1;
  const int m0   = blockIdx.y * 128;
  const int n0   = blockIdx.x * 128;

  f32x4 acc[4][4];
#pragma unroll
  for (int i = 0; i < 4; ++i)
#pragma unroll
    for (int j = 0; j < 4; ++j) zero4(acc[i][j]);

  const int se = wave * 512 + lane * 8;

  const int kt_count = K >> 5;
  for (int kt = 0; kt < kt_count; ++kt) {
    const int k0 = kt << 5;

    bf16x8 av[2], bv[2];
#pragma unroll
    for (int c = 0; c < 2; ++c) {
      const int e   = c * 2048 + se;
      const int row = e >> 5;
      const int col = e & 31;
      av[c] = load8_as_bf16<TA>(&A [(size_t)(m0 + row) * K + k0 + col]);
      bv[c] = load8_as_bf16<TB>(&Bm[(size_t)(n0 + row) * K + k0 + col]);
    }

    __syncthreads();
#pragma unroll
    for (int c = 0; c < 2; ++c) {
      *(bf16x8*)&As[c * 2048 + se] = av[c];
      *(bf16x8*)&Bs[c * 2048 + se] = bv[c];
    }
    __syncthreads();

    bf16x8 af[4], bfv[4];
#pragma unroll
    for (int i = 0; i < 4; ++i)
      af[i] = *(const bf16x8*)&As[(wr * 64 + i * 16 + l15) * 32 + q * 8];
#pragma unroll
    for (int j = 0; j < 4; ++j)
      bfv[j] = *(const bf16x8*)&Bs[(wc * 64 + j * 16 + l15) * 32 + q * 8];

#pragma unroll
    for (int i = 0; i < 4; ++i)
#pragma unroll
      for (int j = 0; j < 4; ++j)
        acc[i][j] = __builtin_amdgcn_mfma_f32_16x16x32_bf16(af[i], bfv[j], acc[i][j], 0, 0, 0);
  }

#pragma unroll
  for (int j = 0; j < 4; ++j) {
    const int n = n0 + wc * 64 + j * 16 + l15;
    const float bvl = bias[n];
#pragma unroll
    for (int i = 0; i < 4; ++i) {
      const int mbase = m0 + wr * 64 + i * 16 + q * 4;
#pragma unroll
      for (int r = 0; r < 4; ++r) {
        float v = acc[i][j][r] + bvl;
        if (relu) v = v > 0.0f ? v : 0.0f;
        C[(size_t)(mbase + r) * N + n] = (bf16_t)v;
      }
    }
  }
}

// ---------------------------------------------------------------------------
// GEMM (bf16 x bf16) with global_load_lds staging (m97 pattern, guide §5:
// 517->874 TF from exactly this change). Both operands must be bf16
// (f32 weights pre-converted once by cvt_f32_bf16).
// ---------------------------------------------------------------------------
__global__ __launch_bounds__(256) void gemm_lds(
    const bf16_t* __restrict__ A, const bf16_t* __restrict__ Bm,
    const float* __restrict__ bias, bf16_t* __restrict__ C,
    int M, int N, int K, int relu)
{
  __shared__ __align__(16) bf16_t As[128 * 32];
  __shared__ __align__(16) bf16_t Bs[128 * 32];

  const int tid  = threadIdx.x;
  const int lane = tid & 63;
  const int wave = tid >> 6;
  const int q    = lane >> 4;
  const int l15  = lane & 15;
  const int wr   = wave >> 1;
  const int wc   = wave & 1;
  const int m0   = blockIdx.y * 128;
  const int n0   = blockIdx.x * 128;

  f32x4 acc[4][4];
#pragma unroll
  for (int i = 0; i < 4; ++i)
#pragma unroll
    for (int j = 0; j < 4; ++j) zero4(acc[i][j]);

  const int sew = wave * 512;          // wave-uniform LDS chunk base (elems)
  const int se  = sew + lane * 8;

  const int kt_count = K >> 5;
  for (int kt = 0; kt < kt_count; ++kt) {
    const int k0 = kt << 5;

    __syncthreads();   // prior iteration's LDS reads complete
#pragma unroll
    for (int c = 0; c < 2; ++c) {
      const int e   = c * 2048 + se;
      const int row = e >> 5;
      const int col = e & 31;
      gload16(&A [(size_t)(m0 + row) * K + k0 + col], &As[c * 2048 + sew]);
      gload16(&Bm[(size_t)(n0 + row) * K + k0 + col], &Bs[c * 2048 + sew]);
    }
    asm volatile("s_waitcnt vmcnt(0)" ::: "memory");
    __syncthreads();   // staging visible to all waves

    bf16x8 af[4], bfv[4];
#pragma unroll
    for (int i = 0; i < 4; ++i)
      af[i] = *(const bf16x8*)&As[(wr * 64 + i * 16 + l15) * 32 + q * 8];
#pragma unroll
    for (int j = 0; j < 4; ++j)
      bfv[j] = *(const bf16x8*)&Bs[(wc * 64 + j * 16 + l15) * 32 + q * 8];

#pragma unroll
    for (int i = 0; i < 4; ++i)
#pragma unroll
      for (int j = 0; j < 4; ++j)
        acc[i][j] = __builtin_amdgcn_mfma_f32_16x16x32_bf16(af[i], bfv[j], acc[i][j], 0, 0, 0);
  }

#pragma unroll
  for (int j = 0; j < 4; ++j) {
    const int n = n0 + wc * 64 + j * 16 + l15;
    const float bvl = bias[n];
#pragma unroll
    for (int i = 0; i < 4; ++i) {
      const int mbase = m0 + wr * 64 + i * 16 + q * 4;
#pragma unroll
      for (int r = 0; r < 4; ++r) {
        float v = acc[i][j][r] + bvl;
        if (relu) v = v > 0.0f ? v : 0.0f;
        C[(size_t)(mbase + r) * N + n] = (bf16_t)v;
      }
    }
  }
}

// ---------------------------------------------------------------------------
// Persistent GRU scan, round 7 = round 6 + FUSED LAYER3.
// Key insight: out_s[b,t] = relu(W3 @ h[b,t]) needs exactly the h fragments
// each wave ALREADY loads for the recurrent matvec. WG owns 4 out_s cols
// (bid*4..+4) -> W3 slice 4x2048 bf16 = 16.4 KB LDS; +16 MFMA/wave/step
// reusing bfr; waves 4-5 (idle during pointwise) reduce+relu+store.
// out_s[:,t-1] computed at step t; out_s[:,127] in an epilogue (flags now
// published at t=127 too). Removes the separate layer3 GEMM (~40 us) and
// raises per-step utilization (DVFS). Sync machinery unchanged from r6.
// ---------------------------------------------------------------------------
#define WROW 2056   // 2048 + 8 bf16 pad
#define NCOPY 8

__global__ __launch_bounds__(512, 2) void gru_persistent(
    const float* __restrict__ W_hh, const float* __restrict__ b_hh,
    const bf16_t* __restrict__ xp, bf16_t* __restrict__ hs,
    unsigned* __restrict__ arr,
    const float* __restrict__ W3, const float* __restrict__ b3,
    bf16_t* __restrict__ out_s)
{
  __shared__ __align__(16) bf16_t Ws[24 * WROW];            // 98,688 B
  __shared__ __align__(16) bf16_t W3s[4 * WROW];            // 16,448 B
  __shared__ __align__(16) float hp_p[8][32][28];           // 28,672 B
  __shared__ __align__(16) float hp3[8][32][8];             //  8,192 B
  __shared__ __align__(16) unsigned short stage[32][8];     //    512 B

  const int tid  = threadIdx.x;
  const int lane = tid & 63;
  const int wave = tid >> 6;      // K-slice owner, 0..7
  const int q    = lane >> 4;
  const int l15  = lane & 15;
  const int bid  = blockIdx.x;
  const int j0   = bid * 8;       // h columns owned
  const int j0s  = bid * 4;       // out_s columns owned
  const int k0w  = wave * 256;

  // ---- Stage W_hh slice into LDS once (f32 -> bf16) ----
  for (int m = 0; m < 24; ++m) {
    const int gate = m >> 3;
    const float* src = W_hh + (size_t)(gate * 2048 + j0 + (m & 7)) * 2048;
    const int c = tid * 4;
    bf16x4 v;
#pragma unroll
    for (int u = 0; u < 4; ++u) v[u] = (bf16_t)src[c + u];
    *(bf16x4*)&Ws[m * WROW + c] = v;
  }
  // ---- Stage W3 slice into LDS once (f32 -> bf16) ----
  for (int m = 0; m < 4; ++m) {
    const float* src = W3 + (size_t)(j0s + m) * 2048;
    const int c = tid * 4;
    bf16x4 v;
#pragma unroll
    for (int u = 0; u < 4; ++u) v[u] = (bf16_t)src[c + u];
    *(bf16x4*)&W3s[m * WROW + c] = v;
  }

  // pointwise mapping: waves 0-3 (tid<256) -> (batch b, local col jj)
  const bool pw = tid < 256;
  const int b  = (tid >> 3) & 31;
  const int jj = tid & 7;
  const int jg = j0 + jj;
  float bh_r = 0.f, bh_z = 0.f, bh_n = 0.f;
  if (pw) {
    bh_r = b_hh[jg];
    bh_z = b_hh[2048 + jg];
    bh_n = b_hh[4096 + jg];
  }
  // out_s reduce mapping: waves 4-5 (tid in [256,384)) -> (batch, col)
  const bool sw = (tid >= 256) && (tid < 384);
  const int b3t = (tid - 256) >> 2;
  const int c3  = (tid - 256) & 3;
  float b3v = 0.f;
  if (sw) b3v = b3[j0s + c3];

  // matmul A-tiles: tile0 row = l15 (gates r,z), tile1 row = 16+(l15&7)
  const bf16_t* arow0 = &Ws[(size_t)l15 * WROW + k0w];
  const bf16_t* arow1 = &Ws[(size_t)(16 + (l15 & 7)) * WROW + k0w];
  // W3 A-tile: rows 0..3 used, lanes l15>=4 duplicate (results discarded)
  const bf16_t* arow3 = &W3s[(size_t)(l15 & 3) * WROW + k0w];

  float hcur = 0.0f;              // this thread's own h(b, jg)

  // xp for t=0
  float xr_c = 0.f, xz_c = 0.f, xn_c = 0.f;
  if (pw) {
    xr_c = (float)xp[(size_t)(b * 128 + 0) * 6144 + jg];
    xz_c = (float)xp[(size_t)(b * 128 + 0) * 6144 + 2048 + jg];
    xn_c = (float)xp[(size_t)(b * 128 + 0) * 6144 + 4096 + jg];
  }

  __syncthreads();   // Ws/W3s staged

  for (int t = 0; t < 128; ++t) {
    if (t > 0) {
      // ---- poll own producer slice of h[t-1] flags (copy bid&7) ----
      const int c = bid & 7;
      const unsigned long long* f64p =
          (const unsigned long long*)(arr + ((size_t)(t - 1) * NCOPY + c) * 256)
          + wave * 16;
      const unsigned long long tgt = 0x0000000100000001ull;
      int guard = 0;
      for (;;) {
        unsigned long long v = tgt;
        if (lane < 16)
          v = __hip_atomic_load(f64p + lane, __ATOMIC_RELAXED,
                                __HIP_MEMORY_SCOPE_AGENT);
        if (__all(v == tgt)) break;
        __builtin_amdgcn_s_sleep(1);
        if (++guard > (1 << 20)) break;   // safety: never hang
      }

      // ---- hprev fragment burst: 16 independent 16B loads ----
      bf16x8 bfr[2][8];
#pragma unroll
      for (int ct = 0; ct < 2; ++ct) {
        const bf16_t* bp_ = hs + ((size_t)(ct * 16 + l15) * 128 + (t - 1)) * 2048
                               + k0w + q * 8;
#pragma unroll
        for (int win = 0; win < 8; ++win)
          bfr[ct][win] = *(const bf16x8*)(bp_ + win * 32);
      }

      f32x4 acc[2][2];
#pragma unroll
      for (int rt = 0; rt < 2; ++rt)
#pragma unroll
        for (int ct = 0; ct < 2; ++ct) zero4(acc[rt][ct]);

#pragma unroll
      for (int win = 0; win < 8; ++win) {
        const bf16x8 a0 = *(const bf16x8*)(arow0 + win * 32 + q * 8);
        const bf16x8 a1 = *(const bf16x8*)(arow1 + win * 32 + q * 8);
        acc[0][0] = __builtin_amdgcn_mfma_f32_16x16x32_bf16(a0, bfr[0][win], acc[0][0], 0, 0, 0);
        acc[0][1] = __builtin_amdgcn_mfma_f32_16x16x32_bf16(a0, bfr[1][win], acc[0][1], 0, 0, 0);
        acc[1][0] = __builtin_amdgcn_mfma_f32_16x16x32_bf16(a1, bfr[0][win], acc[1][0], 0, 0, 0);
        acc[1][1] = __builtin_amdgcn_mfma_f32_16x16x32_bf16(a1, bfr[1][win], acc[1][1], 0, 0, 0);
      }

      // fused layer3: out_s partials for t-1, reusing bfr
      f32x4 acc3[2];
      zero4(acc3[0]); zero4(acc3[1]);
#pragma unroll
      for (int win = 0; win < 8; ++win) {
        const bf16x8 a3 = *(const bf16x8*)(arow3 + win * 32 + q * 8);
        acc3[0] = __builtin_amdgcn_mfma_f32_16x16x32_bf16(a3, bfr[0][win], acc3[0], 0, 0, 0);
        acc3[1] = __builtin_amdgcn_mfma_f32_16x16x32_bf16(a3, bfr[1][win], acc3[1], 0, 0, 0);
      }

      // partials: D col = l15 (batch within ct-tile), row = q*4+reg
#pragma unroll
      for (int ct = 0; ct < 2; ++ct) {
        *(f32x4*)&hp_p[wave][ct * 16 + l15][q * 4] = acc[0][ct];
        if (q < 2)
          *(f32x4*)&hp_p[wave][ct * 16 + l15][16 + q * 4] = acc[1][ct];
      }
      if (q == 0) {   // W3 rows 0..3 live in q==0 lanes
        *(f32x4*)&hp3[wave][l15][0]      = acc3[0];
        *(f32x4*)&hp3[wave][16 + l15][0] = acc3[1];
      }
    }
    __syncthreads();   // (B) partials ready

    float xr_n = 0.f, xz_n = 0.f, xn_n = 0.f;
    if (pw) {
      float pr = 0.0f, pz = 0.0f, pn = 0.0f;
      if (t > 0) {
#pragma unroll
        for (int w = 0; w < 8; ++w) {
          pr += hp_p[w][b][jj];
          pz += hp_p[w][b][8 + jj];
          pn += hp_p[w][b][16 + jj];
        }
      }
      const float r_ = 1.0f / (1.0f + __expf(-(xr_c + pr + bh_r)));
      const float z_ = 1.0f / (1.0f + __expf(-(xz_c + pz + bh_z)));
      const float aa = xn_c + r_ * (pn + bh_n);
      const float et = __expf(-2.0f * aa);
      const float n_ = (1.0f - et) / (1.0f + et);
      hcur = (1.0f - z_) * n_ + z_ * hcur;

      if (t < 127) {
        const int tn = t + 1;
        xr_n = (float)xp[(size_t)(b * 128 + tn) * 6144 + jg];
        xz_n = (float)xp[(size_t)(b * 128 + tn) * 6144 + 2048 + jg];
        xn_n = (float)xp[(size_t)(b * 128 + tn) * 6144 + 4096 + jg];
      }

      union { bf16_t h; unsigned short u; } cv; cv.h = (bf16_t)hcur;
      stage[b][jj] = cv.u;
    } else if (sw && t > 0) {
      // fused layer3 reduce + relu + store out_s[:, t-1]
      float s3 = 0.0f;
#pragma unroll
      for (int w = 0; w < 8; ++w) s3 += hp3[w][b3t][c3];
      s3 += b3v;
      if (s3 < 0.0f) s3 = 0.0f;
      out_s[((size_t)b3t * 128 + (t - 1)) * 1024 + j0s + c3] = (bf16_t)s3;
    }
    __syncthreads();   // (A) stage ready; all LDS reads of step t done

    // ---- packed h store: wave 0 only, 32 x 16B coalesced sc0sc1 ----
    if (wave == 0 && lane < 32) {
      const i32x4 val = *(const i32x4*)&stage[lane][0];
      bf16_t* dst = hs + ((size_t)lane * 128 + t) * 2048 + j0;
      asm volatile("global_store_dwordx4 %0, %1, off sc0 sc1"
                   :: "v"(dst), "v"(val) : "memory");
    }
    if (wave == 0) {
      asm volatile("s_waitcnt vmcnt(0)" ::: "memory");  // stores at LLC
      if (lane < NCOPY)
        __hip_atomic_store(arr + ((size_t)t * NCOPY + lane) * 256 + bid, 1u,
                           __ATOMIC_RELAXED, __HIP_MEMORY_SCOPE_AGENT);
    }
    if (t < 127) {
      xr_c = xr_n; xz_c = xz_n; xn_c = xn_n;
    }
  }

  // ---- epilogue: out_s[:, 127] (needs h[127], flags published above) ----
  {
    const int c = bid & 7;
    const unsigned long long* f64p =
        (const unsigned long long*)(arr + ((size_t)127 * NCOPY + c) * 256)
        + wave * 16;
    const unsigned long long tgt = 0x0000000100000001ull;
    int guard = 0;
    for (;;) {
      unsigned long long v = tgt;
      if (lane < 16)
        v = __hip_atomic_load(f64p + lane, __ATOMIC_RELAXED,
                              __HIP_MEMORY_SCOPE_AGENT);
      if (__all(v == tgt)) break;
      __builtin_amdgcn_s_sleep(1);
      if (++guard > (1 << 20)) break;
    }

    f32x4 acc3[2];
    zero4(acc3[0]); zero4(acc3[1]);
#pragma unroll
    for (int ct = 0; ct < 2; ++ct) {
      const bf16_t* bp_ = hs + ((size_t)(ct * 16 + l15) * 128 + 127) * 2048
                             + k0w + q * 8;
#pragma unroll
      for (int win = 0; win < 8; ++win) {
        const bf16x8 bv = *(const bf16x8*)(bp_ + win * 32);
        const bf16x8 a3 = *(const bf16x8*)(arow3 + win * 32 + q * 8);
        acc3[ct] = __builtin_amdgcn_mfma_f32_16x16x32_bf16(a3, bv, acc3[ct], 0, 0, 0);
      }
    }
    if (q == 0) {
      *(f32x4*)&hp3[wave][l15][0]      = acc3[0];
      *(f32x4*)&hp3[wave][16 + l15][0] = acc3[1];
    }
    __syncthreads();
    if (sw) {
      float s3 = 0.0f;
#pragma unroll
      for (int w = 0; w < 8; ++w) s3 += hp3[w][b3t][c3];
      s3 += b3v;
      if (s3 < 0.0f) s3 = 0.0f;
      out_s[((size_t)b3t * 128 + 127) * 1024 + j0s + c3] = (bf16_t)s3;
    }
  }
}

// ---------------------------------------------------------------------------
// Heads: per (b,t): 3 scalar heads + 4 sigmoid heads, 1024-dot each with a
// label-gathered f32 weight row. out_s is bf16, OUTPUT IS FLOAT32.
// ---------------------------------------------------------------------------
__global__ __launch_bounds__(256) void heads_kernel(
    const bf16_t* __restrict__ out_s, const int* __restrict__ labels,
    const float* __restrict__ W4, const float* __restrict__ b4,
    const float* __restrict__ W5, const float* __restrict__ b5,
    const float* __restrict__ W6, const float* __restrict__ b6,
    const float* __restrict__ Wp, const float* __restrict__ bp,
    float* __restrict__ out)
{
  const int bt  = blockIdx.x;
  const int b   = bt >> 7;         // T = 128
  const int lab = labels[b];
  const bf16_t* os  = out_s + (size_t)bt * 1024;
  const float* w4  = W4 + (size_t)lab * 1024;
  const float* w5  = W5 + (size_t)lab * 1024;
  const float* w6  = W6 + (size_t)lab * 1024;
  const float* wp0 = Wp + (size_t)lab * 1024;   // + p*65536 for plane p

  float s[7] = {0, 0, 0, 0, 0, 0, 0};
  for (int d = threadIdx.x; d < 1024; d += 256) {
    const float v = (float)os[d];
    s[0] += v * w4[d];
    s[1] += v * w5[d];
    s[2] += v * w6[d];
    s[3] += v * wp0[d];
    s[4] += v * wp0[65536 + d];
    s[5] += v * wp0[131072 + d];
    s[6] += v * wp0[196608 + d];
  }
#pragma unroll
  for (int i = 0; i < 7; ++i)
    for (int off = 32; off > 0; off >>= 1)
      s[i] += __shfl_down(s[i], off, 64);

  __shared__ float red[4][7];
  const int lane = threadIdx.x & 63, wave = threadIdx.x >> 6;
  if (lane == 0)
    for (int i = 0; i < 7; ++i) red[wave][i] = s[i];
  __syncthreads();
  if (threadIdx.x == 0) {
    float tsum[7];
    for (int i = 0; i < 7; ++i)
      tsum[i] = red[0][i] + red[1][i] + red[2][i] + red[3][i];
    out[bt]        = tsum[0] + b4[lab];
    out[4096 + bt] = tsum[1] + b5[lab];
    out[8192 + bt] = tsum[2] + b6[lab];
#pragma unroll
    for (int p = 0; p < 4; ++p) {
      const float v = tsum[3 + p] + bp[p * 64 + lab];
      out[12288 + p * 4096 + bt] = 1.0f / (1.0f + __expf(-v));
    }
  }
}

// ---------------------------------------------------------------------------
extern "C" void kernel_launch(void* const* d_in, const int* in_sizes, int n_in,
                              void* d_out, int out_size, void* d_ws, size_t ws_size,
                              hipStream_t stream)
{
  const float* x     = (const float*)d_in[0];
  const int*   label = (const int*)d_in[1];
  const float* W1    = (const float*)d_in[2];
  const float* b1    = (const float*)d_in[3];
  const float* W2    = (const float*)d_in[4];
  const float* b2    = (const float*)d_in[5];
  const float* W_ih  = (const float*)d_in[6];
  const float* b_ih  = (const float*)d_in[7];
  const float* W_hh  = (const float*)d_in[8];
  const float* b_hh  = (const float*)d_in[9];
  const float* W3    = (const float*)d_in[10];
  const float* b3    = (const float*)d_in[11];
  const float* W4    = (const float*)d_in[12];
  const float* b4    = (const float*)d_in[13];
  const float* W5    = (const float*)d_in[14];
  const float* b5    = (const float*)d_in[15];
  const float* W6    = (const float*)d_in[16];
  const float* b6    = (const float*)d_in[17];
  const float* Wp    = (const float*)d_in[18];
  const float* bp    = (const float*)d_in[19];

  // Workspace map (96 MB), bf16 internals. Lifetimes are sequential:
  //   W_ihb [0,24)   bf16 W_ih   (cvt .. xp GEMM)
  //   out2  [24,40)  4096x2048   (layer2 .. xp GEMM)
  //   W2b   [40,44)  bf16 W2     (cvt .. layer2)
  //   out1  [44,52)  4096x1024   (layer1 .. layer2)
  //   xp    [47,95)  4096x6144   (xp GEMM .. GRU)   [reuses out1 region]
  //   hs    [0,16)   (B,T,2048)  (GRU ..)           [reuses W_ihb region]
  //   out_s [16,18)  4096x1024   (GRU .. heads)
  //   arr   [95,96)  flags (memset 0; touched by nothing else)
  char* ws = (char*)d_ws;
  bf16_t* W_ihb = (bf16_t*)(ws);
  bf16_t* out2  = (bf16_t*)(ws + (24u << 20));
  bf16_t* W2b   = (bf16_t*)(ws + (40u << 20));
  bf16_t* out1  = (bf16_t*)(ws + (44u << 20));
  bf16_t* xp    = (bf16_t*)(ws + (47u << 20));
  bf16_t* hs    = (bf16_t*)(ws);
  bf16_t* out_s = (bf16_t*)(ws + (16u << 20));
  unsigned* arr = (unsigned*)(ws + (95u << 20));
  float*  outp  = (float*)d_out;

  hipMemsetAsync(d_out, 0, (size_t)out_size * sizeof(float), stream);
  hipMemsetAsync(arr, 0, 1u << 20, stream);   // arrival flags

  dim3 blk(256);
  // pre-convert f32 weights -> bf16 (enables gload_lds staging)
  cvt_f32_bf16<<<dim3(6144), blk, 0, stream>>>(W_ih, W_ihb, 1572864);
  cvt_f32_bf16<<<dim3(1024), blk, 0, stream>>>(W2, W2b, 262144);
  // layer1: (4096x32)*(1024x32)^T, relu (f32 path, tiny K)
  gemm_bt<float, float><<<dim3(8, 32), blk, 0, stream>>>(x, W1, b1, out1, 4096, 1024, 32, 1);
  // layer2: (4096x1024)*(2048x1024)^T, relu — gload_lds path
  gemm_lds<<<dim3(16, 32), blk, 0, stream>>>(out1, W2b, b2, out2, 4096, 2048, 1024, 1);
  // xp: (4096x2048)*(6144x2048)^T + b_ih — gload_lds path
  gemm_lds<<<dim3(48, 32), blk, 0, stream>>>(out2, W_ihb, b_ih, xp, 4096, 6144, 2048, 0);
  // GRU scan + fused layer3: persistent cooperative kernel
  {
    void* gru_args[] = { (void*)&W_hh, (void*)&b_hh, (void*)&xp, (void*)&hs,
                         (void*)&arr, (void*)&W3, (void*)&b3, (void*)&out_s };
    hipLaunchCooperativeKernel((void*)gru_persistent, dim3(256), dim3(512),
                               gru_args, 0, stream);
  }
  // heads (f32 weights, f32 out)
  heads_kernel<<<dim3(4096), blk, 0, stream>>>(out_s, label, W4, b4, W5, b5, W6, b6, Wp, bp, outp);
}